// Round 14
// baseline (87.380 us; speedup 1.0000x reference)
//
#include <hip/hip_runtime.h>
#include <cstdint>
#include <cstddef>

// Problem constants (from reference): N=16384, D=256.
#define NV 16384
#define DD 256
#define TPB 1024           // k_mis threads (16 waves)
#define BLK 2048           // vertices per sequential phase (VPT=2)
#define PCAP 7             // in-block lower-neighbor cap (fallback exists)
#define HROW 24            // u16 slots per vertex in hi_g: [0]=count, [1..23]=higher nbrs
#define NPASS 12           // probe passes per barrier round

// compiler memory barrier: forces LDS re-reads across passes WITHOUT ordering
// the loads within a pass against each other
#define CFENCE() asm volatile("" ::: "memory")

// ---------------------------------------------------------------------------
// K_prep (parallel, one pass over nbr): per vertex v emit
//  - pend_g[v] (uint4): in-2048-block lower neighbors as u16 offsets
//      x = count | e0<<16 ; y = e1|e2<<16 ; z = e3|e4<<16 ; w = e5|e6<<16
//  - hi_g[v*HROW..]: [count, up to 23 higher-neighbor vertex ids] (u16)
//    (hi rows are LAZILY loaded by k_mis only when v becomes a head)
// ---------------------------------------------------------------------------
__global__ __launch_bounds__(256)
void k_prep(const int* __restrict__ nbr, const int* __restrict__ deg,
            int maxdeg, int n, uint4* __restrict__ pend_g,
            unsigned short* __restrict__ hi_g)
{
    int v = blockIdx.x * 256 + threadIdx.x;
    if (v >= n) return;
    const int b  = v & ~(BLK - 1);
    const int dv = deg[v];
    const int* __restrict__ row = nbr + (size_t)v * (size_t)maxdeg;
    unsigned short* __restrict__ hrow = hi_g + (size_t)v * HROW;
    unsigned w0 = 0, w1 = 0, w2 = 0, w3 = 0;
    int cnt = 0, hic = 0;
    for (int k = 0; k < dv; ++k) {
        int j = row[k];
        if (j > v) {
            if (hic < HROW - 1) hrow[1 + hic] = (unsigned short)j;
            ++hic;
        } else if (j >= b) {
            unsigned val = (unsigned)(j - b);
            switch (cnt) {
                case 0: w0 |= val << 16; break;
                case 1: w1 |= val;       break;
                case 2: w1 |= val << 16; break;
                case 3: w2 |= val;       break;
                case 4: w2 |= val << 16; break;
                case 5: w3 |= val;       break;
                case 6: w3 |= val << 16; break;
                default: break;
            }
            ++cnt;
        }
    }
    hrow[0] = (unsigned short)hic;
    w0 |= (unsigned)(cnt > 0xffff ? 0xffff : cnt);
    pend_g[v] = make_uint4(w0, w1, w2, w3);
}

// PUSH: mark all higher neighbors of new head V as nonhead (hi row lazily
// loaded from global; fallback walks the original nbr row)
__device__ __forceinline__
void do_push(unsigned char* st, int V,
             const unsigned short* __restrict__ hi_g,
             const int* __restrict__ nbr, const int* __restrict__ deg,
             int maxdeg)
{
    const uint4* hp = (const uint4*)(hi_g + (size_t)V * HROW);
    uint4 H0 = hp[0], H1 = hp[1], H2 = hp[2];
    const int hic = (int)(H0.x & 0xffffu);
    if (hic <= HROW - 1) {
        #define PUSHE(word, sh, k) if ((k) < hic) st[((word) >> (sh)) & 0xffffu] = 2
        PUSHE(H0.x,16, 0); PUSHE(H0.y, 0, 1); PUSHE(H0.y,16, 2);
        PUSHE(H0.z, 0, 3); PUSHE(H0.z,16, 4); PUSHE(H0.w, 0, 5);
        PUSHE(H0.w,16, 6);
        PUSHE(H1.x, 0, 7); PUSHE(H1.x,16, 8); PUSHE(H1.y, 0, 9);
        PUSHE(H1.y,16,10); PUSHE(H1.z, 0,11); PUSHE(H1.z,16,12);
        PUSHE(H1.w, 0,13); PUSHE(H1.w,16,14);
        PUSHE(H2.x, 0,15); PUSHE(H2.x,16,16); PUSHE(H2.y, 0,17);
        PUSHE(H2.y,16,18); PUSHE(H2.z, 0,19); PUSHE(H2.z,16,20);
        PUSHE(H2.w, 0,21); PUSHE(H2.w,16,22);
        #undef PUSHE
    } else {
        const int dv = deg[V];
        const int* __restrict__ row = nbr + (size_t)V * (size_t)maxdeg;
        for (int k = 0; k < dv; ++k) {
            int j = row[k];
            if (j > V) st[j] = 2;
        }
    }
}

// DECIDE for one vertex from batched probe values
__device__ __forceinline__
void decide(int& my, unsigned char* st, int V, int np, int qown,
            int q0, int q1, int q2, int q3, int q4, int q5, int q6, int B,
            const unsigned short* __restrict__ hi_g,
            const int* __restrict__ nbr, const int* __restrict__ deg,
            int maxdeg)
{
    if (qown != 0) { my = 2; return; }
    bool anyH = false; int undec = 0;
    if (np <= PCAP) {
        if (np > 0) { anyH |= (q0 == 1); undec += (q0 == 0); }
        if (np > 1) { anyH |= (q1 == 1); undec += (q1 == 0); }
        if (np > 2) { anyH |= (q2 == 1); undec += (q2 == 0); }
        if (np > 3) { anyH |= (q3 == 1); undec += (q3 == 0); }
        if (np > 4) { anyH |= (q4 == 1); undec += (q4 == 0); }
        if (np > 5) { anyH |= (q5 == 1); undec += (q5 == 0); }
        if (np > 6) { anyH |= (q6 == 1); undec += (q6 == 0); }
    } else {
        const int dv = deg[V];
        const int* __restrict__ row = nbr + (size_t)V * (size_t)maxdeg;
        for (int k = 0; k < dv; ++k) {
            int j = row[k];
            if (j >= B && j < V) {
                int q = st[j];
                anyH |= (q == 1); undec += (q == 0);
            }
        }
    }
    if (anyH) { my = 2; st[V] = 2; }
    else if (undec == 0) {
        my = 1; st[V] = 1;
        do_push(st, V, hi_g, nbr, deg, maxdeg);
    }
}

// ---------------------------------------------------------------------------
// K_mis: lexicographic greedy MIS, single WG of 1024 threads (16 waves), PUSH.
// VPT=2: thread t owns v0=b+t and v1=b+1024+t of the current 2048-block ->
// only 8 sequential barrier phases. st: 0=unknown,1=head,2=nonhead (monotone).
// Out-of-block verdict = own st[v] read (pushed by earlier heads). hi push
// lists are loaded from global LAZILY at head-decision time (~2900 total,
// L2-hot) instead of being prefetched for every vertex. Per round: up to
// NPASS batched probe passes with a compiler fence between passes; per-wave
// ballot early-exit; one drain-free barrier per round (lgkmcnt only).
// ---------------------------------------------------------------------------
__global__ __launch_bounds__(TPB, 4)
void k_mis(const int* __restrict__ nbr, const int* __restrict__ deg,
           int maxdeg, int n,
           const uint4* __restrict__ pend_g, const unsigned short* __restrict__ hi_g,
           int* __restrict__ headlist, float* __restrict__ out_tail)
{
    __shared__ __align__(16) unsigned char st[NV];
    __shared__ int s_ws[TPB / 64];
    __shared__ int F[3];
    const int t    = threadIdx.x;
    const int lane = t & 63;
    const int wid  = t >> 6;

    ((uint4*)st)[t] = make_uint4(0u, 0u, 0u, 0u);   // 1024*16B == NV
    if (t < 3) F[t] = 0;
    __syncthreads();

    // prefetch block 0 pend (2 vertices/thread), double-buffered across blocks
    uint4 pa0 = make_uint4(0,0,0,0), pa1 = pa0;
    if (t < n)        pa0 = pend_g[t];
    if (1024 + t < n) pa1 = pend_g[1024 + t];
    int r = 0;

    for (int b = 0; b < n; b += BLK) {
        const int v0 = b + t, v1 = b + 1024 + t;
        // prefetch next block pend; stays in flight across drain-free barriers
        uint4 qa0 = make_uint4(0,0,0,0), qa1 = qa0;
        {
            int w0 = b + BLK + t, w1 = b + BLK + 1024 + t;
            if (w0 < n) qa0 = pend_g[w0];
            if (w1 < n) qa1 = pend_g[w1];
        }

        const int np0 = pa0.x & 0xffff;
        const int e0 = pa0.x >> 16,    e1 = pa0.y & 0xffff, e2 = pa0.y >> 16;
        const int e3 = pa0.z & 0xffff, e4 = pa0.z >> 16;
        const int e5 = pa0.w & 0xffff, e6 = pa0.w >> 16;
        const int np1 = pa1.x & 0xffff;
        const int f0 = pa1.x >> 16,    f1 = pa1.y & 0xffff, f2 = pa1.y >> 16;
        const int f3 = pa1.z & 0xffff, f4 = pa1.z >> 16;
        const int f5 = pa1.w & 0xffff, f6 = pa1.w >> 16;

        int my0 = (v0 < n) ? 0 : 2;
        int my1 = (v1 < n) ? 0 : 2;

        for (;; ++r) {
            if (t == 0) F[(r + 1) % 3] = 0;
            for (int pass = 0; pass < NPASS; ++pass) {
                // batched INDEPENDENT probes for both vertices (one wait)
                int s0  = st[v0 < n ? v0 : 0],  s1  = st[v1 < n ? v1 : 0];
                int q00 = st[b + e0], q01 = st[b + e1], q02 = st[b + e2];
                int q03 = st[b + e3], q04 = st[b + e4], q05 = st[b + e5];
                int q06 = st[b + e6];
                int q10 = st[b + f0], q11 = st[b + f1], q12 = st[b + f2];
                int q13 = st[b + f3], q14 = st[b + f4], q15 = st[b + f5];
                int q16 = st[b + f6];
                if (my0 == 0) decide(my0, st, v0, np0, s0,
                                     q00,q01,q02,q03,q04,q05,q06, b,
                                     hi_g, nbr, deg, maxdeg);
                if (my1 == 0) decide(my1, st, v1, np1, s1,
                                     q10,q11,q12,q13,q14,q15,q16, b,
                                     hi_g, nbr, deg, maxdeg);
                if (__ballot((my0 == 0) || (my1 == 0)) == 0ULL) break;
                CFENCE();   // force genuine LDS re-reads next pass
            }
            if ((my0 == 0) || (my1 == 0)) F[r % 3] = 1;
            // drain-free barrier: LDS visible, global prefetch stays in flight
            asm volatile("s_waitcnt lgkmcnt(0)\n\ts_barrier" ::: "memory");
            if (F[r % 3] == 0) { ++r; break; }
        }
        pa0 = qa0; pa1 = qa1;
    }

    // ---- epilogue: count heads, scan, emit headlist / head_mask / count ----
    uint4 qq = ((const uint4*)st)[t];          // thread t owns bytes [16t,16t+16)
    int cnt = __popc(qq.x & 0x01010101u) + __popc(qq.y & 0x01010101u)
            + __popc(qq.z & 0x01010101u) + __popc(qq.w & 0x01010101u);
    int c = cnt;
    #pragma unroll
    for (int off = 1; off < 64; off <<= 1) {
        int x = __shfl_up(c, off);
        if (lane >= off) c += x;
    }
    if (lane == 63) s_ws[wid] = c;
    __syncthreads();
    int wexcl = 0, tot = 0;
    #pragma unroll
    for (int w = 0; w < TPB / 64; ++w) {
        int s = s_ws[w];
        tot += s;
        if (w < wid) wexcl += s;
    }
    int excl = wexcl + (c - cnt);
    #pragma unroll
    for (int i = 0; i < 16; ++i) {
        int v = t * 16 + i;
        if (st[v] == 1) { headlist[excl] = v; ++excl; }
    }
    for (int i = t; i < NV / 4; i += TPB) {
        unsigned w = ((const unsigned*)st)[i];
        float4 f;
        f.x = (float)(w & 1u);         f.y = (float)((w >> 8) & 1u);
        f.z = (float)((w >> 16) & 1u); f.w = (float)((w >> 24) & 1u);
        ((float4*)out_tail)[i] = f;
    }
    if (t == 0) out_tail[n] = (float)tot;
}

// ---------------------------------------------------------------------------
// K_avg (fused owner+avg): one 64-lane wave per output row.
// Waves [0,tot): cluster mean for h=headlist[w]. Candidate j in row(h) is a
// member iff j nonhead AND min{head nbrs of j} == h (walk j's row in-lane;
// j<h auto-excluded since its min head nbr < j < h).
// Waves [tot,n): zero-fill the row (replaces the memset).
// ---------------------------------------------------------------------------
__global__ __launch_bounds__(256)
void k_avg(const float* __restrict__ vert, const int* __restrict__ nbr,
           const int* __restrict__ deg, int maxdeg, int n,
           const int* __restrict__ headlist,
           const float* __restrict__ tail, float* __restrict__ out)
{
    const int w    = (blockIdx.x * 256 + threadIdx.x) >> 6;
    const int lane = threadIdx.x & 63;
    if (w >= n) return;
    const int tot  = (int)tail[n];
    if (w >= tot) {
        reinterpret_cast<float4*>(out + (size_t)w * DD)[lane] = make_float4(0.f, 0.f, 0.f, 0.f);
        return;
    }
    const int h = headlist[w];

    const int dh = deg[h];
    const int* __restrict__ row = nbr + (size_t)h * (size_t)maxdeg;

    float4 acc = reinterpret_cast<const float4*>(vert + (size_t)h * DD)[lane];
    int cnt = 1;

    for (int k0 = 0; k0 < dh; k0 += 64) {
        int k = k0 + lane;
        int j = (k < dh) ? row[k] : -1;
        bool mem = false;
        if (j > h && tail[j] == 0.0f) {        // nonhead, higher candidate
            const int dj = deg[j];
            const int* __restrict__ rj = nbr + (size_t)j * (size_t)maxdeg;
            int mn = 0x7fffffff;
            for (int kk = 0; kk < dj; ++kk) {
                int u = rj[kk];
                if (tail[u] != 0.0f) mn = min(mn, u);
            }
            mem = (mn == h);
        }
        unsigned long long m = __ballot(mem);
        cnt += __popcll(m);
        while (m) {
            int bit = __ffsll((long long)m) - 1;
            m &= (m - 1);
            int jj = __shfl(j, bit);
            float4 rr = reinterpret_cast<const float4*>(vert + (size_t)jj * DD)[lane];
            acc.x += rr.x; acc.y += rr.y; acc.z += rr.z; acc.w += rr.w;
        }
    }
    const float inv = 1.0f / (float)cnt;
    float4 res;
    res.x = acc.x * inv; res.y = acc.y * inv;
    res.z = acc.z * inv; res.w = acc.w * inv;
    reinterpret_cast<float4*>(out + (size_t)w * DD)[lane] = res;
}

// ---------------------------------------------------------------------------
extern "C" void kernel_launch(void* const* d_in, const int* in_sizes, int n_in,
                              void* d_out, int out_size, void* d_ws, size_t ws_size,
                              hipStream_t stream)
{
    const float* vert = (const float*)d_in[0];
    const int*   nbr  = (const int*)d_in[1];
    const int*   deg  = (const int*)d_in[2];

    const int n      = in_sizes[2];            // 16384
    const int maxdeg = in_sizes[1] / n;
    const int d      = in_sizes[0] / n;        // 256

    int*   headlist = (int*)d_ws;                                  // n ints
    uint4* pend_g   = (uint4*)(headlist + n);                      // n uint4 (256KB)
    unsigned short* hi_g = (unsigned short*)(pend_g + n);          // n * HROW u16

    float* out      = (float*)d_out;
    float* out_tail = out + (size_t)n * (size_t)d;   // head_mask .. num_clusters

    hipLaunchKernelGGL(k_prep, dim3((n + 255) / 256), dim3(256), 0, stream,
                       nbr, deg, maxdeg, n, pend_g, hi_g);

    hipLaunchKernelGGL(k_mis, dim3(1), dim3(TPB), 0, stream,
                       nbr, deg, maxdeg, n, pend_g, hi_g, headlist, out_tail);

    const int blocks = (n * 64 + 255) / 256;   // one wave per output row
    hipLaunchKernelGGL(k_avg, dim3(blocks), dim3(256), 0, stream,
                       vert, nbr, deg, maxdeg, n, headlist, out_tail, out);
}